// Round 1
// baseline (678.139 us; speedup 1.0000x reference)
//
#include <hip/hip_runtime.h>

// VanillaLstmEncDec: fused persistent-per-block LSTM enc(8 steps)+dec(11 steps).
// Each block owns 128 batch rows for the whole sequence: h in LDS (bf16),
// c in f32 registers. Rank-2 input embedding folded into the hidden matmul
// via extra K-slots: A = [h(128) | px_hi, py_hi, 1 | px_lo, py_lo | 0...], K=160.
// Weights pre-transposed+folded to bf16 in d_ws by a prep kernel.

#define OBS_LEN 8
#define PRED_LEN 12
#define BATCH 131072
#define HID 128
#define NZ 512          // 4*HID gate columns
#define KW 160          // weight K (128 h + px,py,1,px_lo,py_lo + pad)
#define KP 168          // LDS A row stride in elems (336B rows -> 2-way bank alias, free)

typedef float f32x4 __attribute__((ext_vector_type(4)));
typedef unsigned short u16x8 __attribute__((ext_vector_type(8)));
typedef __bf16 bf16x8 __attribute__((ext_vector_type(8)));

static __device__ __forceinline__ unsigned short f2bf(float f) {
  unsigned int u = __float_as_uint(f);
  u += 0x7FFFu + ((u >> 16) & 1u);   // round-to-nearest-even
  return (unsigned short)(u >> 16);
}
static __device__ __forceinline__ float bf2f(unsigned short h) {
  return __uint_as_float(((unsigned int)h) << 16);
}
static __device__ __forceinline__ float sigf(float x) {
  return __builtin_amdgcn_rcpf(1.f + __builtin_amdgcn_exp2f(-1.4426950408889634f * x));
}
static __device__ __forceinline__ float tanh_f(float x) {
  float e = __builtin_amdgcn_exp2f(2.8853900817779268f * x);
  return 1.f - 2.f * __builtin_amdgcn_rcpf(e + 1.f);
}

// ---------------- prep: build folded, transposed bf16 weights ----------------
// WT[n][k], n in [0,512), k in [0,160):
//   k<128        : Whh[k][n]
//   k=128 / 131  : (Wemb@Wih)[0][n]   (px weight, duplicated for hi/lo split)
//   k=129 / 132  : (Wemb@Wih)[1][n]   (py weight)
//   k=130        : bemb@Wih[n] + b[n] (bias, multiplied by constant-1 slot)
//   else         : 0
__global__ void prep_weights(const float* __restrict__ We,   const float* __restrict__ be,
                             const float* __restrict__ Wih_e,const float* __restrict__ Whh_e,
                             const float* __restrict__ b_e,
                             const float* __restrict__ Wd,   const float* __restrict__ bd,
                             const float* __restrict__ Wih_d,const float* __restrict__ Whh_d,
                             const float* __restrict__ b_d,
                             unsigned short* __restrict__ wt_enc,
                             unsigned short* __restrict__ wt_dec) {
  int n = blockIdx.x & (NZ - 1);
  bool dec = blockIdx.x >= NZ;
  const float* Whh = dec ? Whh_d : Whh_e;
  const float* Wih = dec ? Wih_d : Wih_e;
  const float* Wem = dec ? Wd : We;
  const float* bem = dec ? bd : be;
  const float* bl  = dec ? b_d : b_e;
  unsigned short* wt = dec ? wt_dec : wt_enc;
  for (int k = threadIdx.x; k < KW; k += blockDim.x) {
    float v = 0.f;
    if (k < HID) {
      v = Whh[k * NZ + n];
    } else if (k == 130) {
      float s = bl[n];
      for (int e = 0; e < HID; ++e) s += bem[e] * Wih[e * NZ + n];
      v = s;
    } else if (k <= 132) {  // 128,129,131,132
      int which = (k == 129 || k == 132) ? 1 : 0;
      float s = 0.f;
      for (int e = 0; e < HID; ++e) s += Wem[which * HID + e] * Wih[e * NZ + n];
      v = s;
    }
    wt[n * KW + k] = f2bf(v);
  }
}

// ---------------- main fused kernel ----------------
// 512 threads = 8 waves. Wave wn owns ALL 128 rows x hidden slice [16*wn,16*wn+16)
// across all 4 gates -> gate combine + c-state are register-local per lane.
// MFMA 16x16x32 bf16: A row = lane&15, k = 32*kc + (lane>>4)*8 + j;
// B col = lane&15, same k; C/D row = (lane>>4)*4 + reg, col = lane&15.

#define LSTM_STEP(WT)                                                          \
  {                                                                            \
    _Pragma("unroll")                                                          \
    for (int m = 0; m < 8; ++m) {                                              \
      _Pragma("unroll")                                                        \
      for (int g = 0; g < 4; ++g) acc[m][g] = zero4;                           \
    }                                                                          \
    _Pragma("unroll")                                                          \
    for (int kc = 0; kc < 5; ++kc) {                                           \
      const int k0 = kc * 32 + l4 * 8;                                         \
      u16x8 afr[8];                                                            \
      _Pragma("unroll")                                                        \
      for (int m = 0; m < 8; ++m)                                              \
        afr[m] = *(const u16x8*)&Als[(16 * m + l15) * KP + k0];                \
      _Pragma("unroll")                                                        \
      for (int g = 0; g < 4; ++g) {                                            \
        u16x8 bfr = *(const u16x8*)&(WT)[(g * 128 + wn * 16 + l15) * KW + k0]; \
        _Pragma("unroll")                                                      \
        for (int m = 0; m < 8; ++m)                                            \
          acc[m][g] = __builtin_amdgcn_mfma_f32_16x16x32_bf16(                 \
              __builtin_bit_cast(bf16x8, afr[m]),                              \
              __builtin_bit_cast(bf16x8, bfr), acc[m][g], 0, 0, 0);            \
      }                                                                        \
    }                                                                          \
    __syncthreads(); /* all waves done reading A before h overwrite */         \
    _Pragma("unroll")                                                          \
    for (int m = 0; m < 8; ++m) {                                              \
      _Pragma("unroll")                                                        \
      for (int r = 0; r < 4; ++r) {                                            \
        float zi = acc[m][0][r], zf = acc[m][1][r];                            \
        float zg = acc[m][2][r], zo = acc[m][3][r];                            \
        float c = sigf(zf) * cr[m][r] + sigf(zi) * tanh_f(zg);                 \
        cr[m][r] = c;                                                          \
        float h = sigf(zo) * tanh_f(c);                                        \
        Als[(16 * m + l4 * 4 + r) * KP + wn * 16 + l15] = f2bf(h);             \
      }                                                                        \
    }                                                                          \
  }

#define POS_PHASE(S)                                                           \
  {                                                                            \
    __syncthreads(); /* h visible */                                           \
    const int r = tid >> 2, q = tid & 3;                                       \
    float sx = 0.f, sy = 0.f;                                                  \
    _Pragma("unroll")                                                          \
    for (int kb = 0; kb < 4; ++kb) {                                           \
      u16x8 hv = *(const u16x8*)&Als[r * KP + q * 32 + kb * 8];                \
      _Pragma("unroll")                                                        \
      for (int j = 0; j < 8; ++j) {                                            \
        int k = q * 32 + kb * 8 + j;                                           \
        float h = bf2f(hv[j]);                                                 \
        sx += h * WoL[k][0];                                                   \
        sy += h * WoL[k][1];                                                   \
      }                                                                        \
    }                                                                          \
    sx += __shfl_xor(sx, 1); sx += __shfl_xor(sx, 2);                          \
    sy += __shfl_xor(sy, 1); sy += __shfl_xor(sy, 2);                          \
    if (q == 0) {                                                              \
      float px = sx + bo0, py = sy + bo1;                                      \
      float2 o; o.x = px; o.y = py;                                            \
      ((float2*)out)[(size_t)(S) * BATCH + row0 + r] = o;                      \
      unsigned short hx = f2bf(px), hy = f2bf(py);                             \
      Als[r * KP + 128] = hx;                                                  \
      Als[r * KP + 129] = hy;                                                  \
      Als[r * KP + 131] = f2bf(px - bf2f(hx)); /* lo residual */               \
      Als[r * KP + 132] = f2bf(py - bf2f(hy));                                 \
    }                                                                          \
  }

__global__ __launch_bounds__(512, 2) void lstm_fused(
    const float* __restrict__ obs,
    const unsigned short* __restrict__ wt_enc,
    const unsigned short* __restrict__ wt_dec,
    const float* __restrict__ Wo, const float* __restrict__ bo,
    float* __restrict__ out) {
  __shared__ unsigned short Als[128 * KP];
  __shared__ float WoL[HID][2];

  const int tid = threadIdx.x;
  const int lane = tid & 63;
  const int wn = tid >> 6;        // 0..7: hidden slice [16wn, 16wn+16)
  const int l15 = lane & 15;
  const int l4 = lane >> 4;
  const int row0 = blockIdx.x * 128;
  const f32x4 zero4 = {0.f, 0.f, 0.f, 0.f};

  for (int i = tid; i < 128 * KP; i += 512) Als[i] = 0;  // h=0, pads=0
  if (tid < HID) { WoL[tid][0] = Wo[tid * 2]; WoL[tid][1] = Wo[tid * 2 + 1]; }
  const float bo0 = bo[0], bo1 = bo[1];
  __syncthreads();
  if (tid < 128) Als[tid * KP + 130] = 0x3F80u;  // constant-1 slot (bias)

  f32x4 acc[8][4];   // [m-tile][gate]
  float cr[8][4];    // c state, f32 forever
#pragma unroll
  for (int m = 0; m < 8; ++m) {
#pragma unroll
    for (int r = 0; r < 4; ++r) cr[m][r] = 0.f;
  }

  // ---- encoder: 8 steps, x = obs[t] ----
  for (int t = 0; t < OBS_LEN; ++t) {
    if (tid < 128) {
      float2 p = ((const float2*)obs)[(size_t)t * BATCH + row0 + tid];
      unsigned short hx = f2bf(p.x), hy = f2bf(p.y);
      Als[tid * KP + 128] = hx;
      Als[tid * KP + 129] = hy;
      Als[tid * KP + 131] = f2bf(p.x - bf2f(hx));
      Als[tid * KP + 132] = f2bf(p.y - bf2f(hy));
    }
    __syncthreads();  // px/h visible to MFMA
    LSTM_STEP(wt_enc);
  }

  // ---- pos0 from h_enc; reset c for decoder ----
  POS_PHASE(0);
#pragma unroll
  for (int m = 0; m < 8; ++m) {
#pragma unroll
    for (int r = 0; r < 4; ++r) cr[m][r] = 0.f;
  }

  // ---- decoder: 11 steps, x = pos_prev (folded) ----
  for (int s = 1; s < PRED_LEN; ++s) {
    __syncthreads();  // pos writes visible
    LSTM_STEP(wt_dec);
    POS_PHASE(s);
  }
}

extern "C" void kernel_launch(void* const* d_in, const int* in_sizes, int n_in,
                              void* d_out, int out_size, void* d_ws, size_t ws_size,
                              hipStream_t stream) {
  const float* obs   = (const float*)d_in[0];
  const float* We    = (const float*)d_in[1];
  const float* be    = (const float*)d_in[2];
  const float* Wih_e = (const float*)d_in[3];
  const float* Whh_e = (const float*)d_in[4];
  const float* b_e   = (const float*)d_in[5];
  const float* Wd    = (const float*)d_in[6];
  const float* bd    = (const float*)d_in[7];
  const float* Wih_d = (const float*)d_in[8];
  const float* Whh_d = (const float*)d_in[9];
  const float* b_d   = (const float*)d_in[10];
  const float* Wo    = (const float*)d_in[11];
  const float* bo    = (const float*)d_in[12];
  float* out = (float*)d_out;

  unsigned short* wt_enc = (unsigned short*)d_ws;           // 512*160*2 B
  unsigned short* wt_dec = wt_enc + NZ * KW;                // +160 KB

  hipLaunchKernelGGL(prep_weights, dim3(2 * NZ), dim3(64), 0, stream,
                     We, be, Wih_e, Whh_e, b_e, Wd, bd, Wih_d, Whh_d, b_d,
                     wt_enc, wt_dec);
  hipLaunchKernelGGL(lstm_fused, dim3(BATCH / 128), dim3(512), 0, stream,
                     obs, wt_enc, wt_dec, Wo, bo, out);
}